// Round 1
// 180.282 us; speedup vs baseline: 1.0224x; 1.0224x over previous
//
#include <hip/hip_runtime.h>
#include <hip/hip_bf16.h>

#define B_SZ 8
#define LSEQ 200
#define DMODEL 256
#define DINNER 512
#define DSTATE 64
#define DTRANK 16
#define ROWS (B_SZ * LSEQ)   // 1600

using bf16x8 = __attribute__((ext_vector_type(8))) short;
using f32x4  = __attribute__((ext_vector_type(4))) float;

__device__ __forceinline__ float softplusf(float x) {
    return (x > 20.f) ? x : log1pf(__expf(x));
}
__device__ __forceinline__ float siluf(float x) {
    return x / (1.f + __expf(-x));
}
__device__ __forceinline__ unsigned short f2bf(float f) {
    union { float f; unsigned int u; } v; v.f = f;
    unsigned int r = v.u + 0x7FFF + ((v.u >> 16) & 1);   // RNE
    return (unsigned short)(r >> 16);
}
__device__ __forceinline__ float bf2f(unsigned short u) {
    union { unsigned int i; float f; } v;
    v.i = ((unsigned int)u) << 16;
    return v.f;
}

// ---------------------------------------------------------------------------
// One-time prep: split x into bf16 hi/lo; transpose+split W_in, W_x, W_out
// into [N][K] k-contiguous bf16 hi/lo (B-operand layout for MFMA).
// ---------------------------------------------------------------------------
__global__ __launch_bounds__(256) void prep_w_k(
    const float* __restrict__ x, const float* __restrict__ W_in,
    const float* __restrict__ W_x, const float* __restrict__ W_out,
    unsigned short* __restrict__ x_hi,  unsigned short* __restrict__ x_lo,
    unsigned short* __restrict__ WiT_hi, unsigned short* __restrict__ WiT_lo,
    unsigned short* __restrict__ WxT_hi, unsigned short* __restrict__ WxT_lo,
    unsigned short* __restrict__ WoT_hi, unsigned short* __restrict__ WoT_lo)
{
    int idx = blockIdx.x * 256 + threadIdx.x;
    float v;
    unsigned short *dh, *dl;
    size_t di;
    if (idx < 409600) {                       // x: straight split (k-contig already)
        v = x[idx]; dh = x_hi; dl = x_lo; di = idx;
    } else if (idx < 409600 + 262144) {       // W_in [256][1024] -> WiT [1024][256]
        int l = idx - 409600;
        int n = l >> 8, k = l & 255;
        v = W_in[(size_t)k * 1024 + n]; dh = WiT_hi; dl = WiT_lo; di = l;  // l == n*256+k
    } else if (idx < 409600 + 262144 + 73728) { // W_x [512][144] -> WxT [144][512]
        int l = idx - (409600 + 262144);
        int n = l >> 9, k = l & 511;
        v = W_x[(size_t)k * 144 + n]; dh = WxT_hi; dl = WxT_lo; di = l;    // l == n*512+k
    } else if (idx < 409600 + 262144 + 73728 + 131072) { // W_out [512][256] -> WoT [256][512]
        int l = idx - (409600 + 262144 + 73728);
        int n = l >> 9, k = l & 511;
        v = W_out[(size_t)k * 256 + n]; dh = WoT_hi; dl = WoT_lo; di = l;  // l == n*512+k
    } else return;
    unsigned short h = f2bf(v);
    dh[di] = h;
    dl[di] = f2bf(v - bf2f(h));
}

// ---------------------------------------------------------------------------
// Split-bf16 MFMA GEMM: C[M,N] = A[M,K]·B[K,N] (+resid), fp32-accurate via
// hi·hi + hi·lo + lo·hi. A as split bf16 [M][K]; B as split bf16 [N][K]
// (transposed, k-contig). 64x64 block tile, 4 waves of 32x32, BK=32.
// M mult of 64, K mult of 32, N guarded.
// ---------------------------------------------------------------------------
__global__ __launch_bounds__(256) void gemm_mfma(
    const unsigned short* __restrict__ A_hi, const unsigned short* __restrict__ A_lo,
    const unsigned short* __restrict__ BT_hi, const unsigned short* __restrict__ BT_lo,
    float* __restrict__ C, int M, int N, int K, const float* __restrict__ resid)
{
    __shared__ unsigned short As_hi[64 * 40], As_lo[64 * 40];  // row stride 40 bf16
    __shared__ unsigned short Bs_hi[64 * 40], Bs_lo[64 * 40];

    const int t    = threadIdx.x;
    const int m0   = blockIdx.y * 64;
    const int n0   = blockIdx.x * 64;
    const int lane = t & 63;
    const int w    = t >> 6;
    const int wm   = (w >> 1) * 32;
    const int wn   = (w & 1) * 32;
    const int fr   = lane & 15;     // frag m (A) / n (B) index
    const int fq   = lane >> 4;     // frag quad: k-offset fq*8; D-row fq*4+reg

    const int sr = t >> 2;          // staging row 0..63
    const int sc = (t & 3) * 8;     // staging col 0,8,16,24

    f32x4 acc[2][2] = {};

    const size_t a_off = (size_t)(m0 + sr) * K + sc;
    const int    brow  = n0 + sr;
    const size_t b_off = (size_t)brow * K + sc;
    const bool   bok   = brow < N;

    for (int k0 = 0; k0 < K; k0 += 32) {
        int4 ah = *(const int4*)(A_hi + a_off + k0);
        int4 al = *(const int4*)(A_lo + a_off + k0);
        int4 bh = make_int4(0, 0, 0, 0), bl = make_int4(0, 0, 0, 0);
        if (bok) {
            bh = *(const int4*)(BT_hi + b_off + k0);
            bl = *(const int4*)(BT_lo + b_off + k0);
        }
        __syncthreads();   // previous iteration's frag reads done
        *(int4*)&As_hi[sr * 40 + sc] = ah;
        *(int4*)&As_lo[sr * 40 + sc] = al;
        *(int4*)&Bs_hi[sr * 40 + sc] = bh;
        *(int4*)&Bs_lo[sr * 40 + sc] = bl;
        __syncthreads();

        bf16x8 a_h[2], a_l[2], b_h[2], b_l[2];
#pragma unroll
        for (int mi = 0; mi < 2; mi++) {
            int row = wm + mi * 16 + fr;
            a_h[mi] = *(const bf16x8*)&As_hi[row * 40 + fq * 8];
            a_l[mi] = *(const bf16x8*)&As_lo[row * 40 + fq * 8];
        }
#pragma unroll
        for (int ni = 0; ni < 2; ni++) {
            int row = wn + ni * 16 + fr;
            b_h[ni] = *(const bf16x8*)&Bs_hi[row * 40 + fq * 8];
            b_l[ni] = *(const bf16x8*)&Bs_lo[row * 40 + fq * 8];
        }
#pragma unroll
        for (int mi = 0; mi < 2; mi++)
#pragma unroll
            for (int ni = 0; ni < 2; ni++) {
                acc[mi][ni] = __builtin_amdgcn_mfma_f32_16x16x32_bf16(a_h[mi], b_h[ni], acc[mi][ni], 0, 0, 0);
                acc[mi][ni] = __builtin_amdgcn_mfma_f32_16x16x32_bf16(a_h[mi], b_l[ni], acc[mi][ni], 0, 0, 0);
                acc[mi][ni] = __builtin_amdgcn_mfma_f32_16x16x32_bf16(a_l[mi], b_h[ni], acc[mi][ni], 0, 0, 0);
            }
    }

#pragma unroll
    for (int mi = 0; mi < 2; mi++)
#pragma unroll
        for (int ni = 0; ni < 2; ni++) {
            int col = n0 + wn + ni * 16 + fr;
            if (col < N) {
#pragma unroll
                for (int reg = 0; reg < 4; reg++) {
                    int row = m0 + wm + mi * 16 + fq * 4 + reg;
                    float v = acc[mi][ni][reg];
                    if (resid) v += resid[(size_t)row * N + col];
                    C[(size_t)row * N + col] = v;
                }
            }
        }
}

// ---------------------------------------------------------------------------
// Depthwise causal conv (width 4) + bias + silu; emits fp32 + split bf16.
// ---------------------------------------------------------------------------
__global__ __launch_bounds__(256) void conv_silu_k(
    const float* __restrict__ xz, const float* __restrict__ conv_w,
    const float* __restrict__ conv_b, float* __restrict__ xm,
    unsigned short* __restrict__ xm_hi, unsigned short* __restrict__ xm_lo)
{
    int idx = blockIdx.x * 256 + threadIdx.x;   // < ROWS*512 = 819200
    int c = idx & 511;
    int r = idx >> 9;
    int l = r % LSEQ;

    float w0 = conv_w[c * 4 + 0];
    float w1 = conv_w[c * 4 + 1];
    float w2 = conv_w[c * 4 + 2];
    float w3 = conv_w[c * 4 + 3];

    const float* base = xz + (size_t)r * 1024 + c;
    float acc = conv_b[c];
    if (l >= 3) acc = fmaf(base[-3 * 1024], w0, acc);
    if (l >= 2) acc = fmaf(base[-2 * 1024], w1, acc);
    if (l >= 1) acc = fmaf(base[-1 * 1024], w2, acc);
    acc = fmaf(base[0], w3, acc);

    float s = siluf(acc);
    xm[idx] = s;
    unsigned short h = f2bf(s);
    xm_hi[idx] = h;
    xm_lo[idx] = f2bf(s - bf2f(h));
}

// ---------------------------------------------------------------------------
// Pack B and C (with phase modulation) interleaved per row.
// ---------------------------------------------------------------------------
__global__ __launch_bounds__(256) void pack_bc_k(
    const float* __restrict__ cosp, const float* __restrict__ sinp,
    const float* __restrict__ W_phase, const float* __restrict__ xp,
    float* __restrict__ bcp)
{
    int idx = blockIdx.x * 256 + threadIdx.x;   // < ROWS*64 = 102400
    int n = idx & 63;
    int r = idx >> 6;
    int b = r / LSEQ, l = r % LSEQ;

    float acc = 0.f;
#pragma unroll
    for (int j = 0; j < 4; j++) {
        float cp = cosp[(b * 4 + j) * LSEQ + l];
        float sp = sinp[(b * 4 + j) * LSEQ + l];
        acc = fmaf(cp, W_phase[j * 64 + n], acc);
        acc = fmaf(sp, W_phase[(4 + j) * 64 + n], acc);
    }
    float Bv = xp[(size_t)r * 144 + 16 + n];
    float Cv = xp[(size_t)r * 144 + 80 + n] + acc;
    *(float2*)&bcp[(size_t)r * 128 + 2 * n] = make_float2(Bv, Cv);
}

// ---------------------------------------------------------------------------
// dt kernel; writes dtpack[r*512+d] = (dt, dt*u)  -- l-major, coalesced.
// ---------------------------------------------------------------------------
__global__ __launch_bounds__(256) void dt_k(
    const float* __restrict__ xp, const float* __restrict__ W_dt,
    const float* __restrict__ b_dt, const float* __restrict__ dmag,
    const float* __restrict__ xm, float2* __restrict__ dtpack)
{
    int r = blockIdx.x;          // 0..1599
    int t = threadIdx.x;
    int b = r / LSEQ, l = r % LSEQ;

    __shared__ float xr[16];
    __shared__ float sscale;
    if (t < 16) xr[t] = xp[(size_t)r * 144 + t];
    if (t == 16) {
        float dm = 0.f;
#pragma unroll
        for (int j = 0; j < 4; j++)
            dm += dmag[(b * 4 + j) * LSEQ + l];
        dm *= 0.25f;
        sscale = 1.f + softplusf(dm);
    }
    __syncthreads();
    float scale = sscale;

#pragma unroll
    for (int rep = 0; rep < 2; rep++) {
        int d = t + rep * 256;
        float acc = b_dt[d];
#pragma unroll
        for (int i = 0; i < 16; i++)
            acc = fmaf(xr[i], W_dt[i * 512 + d], acc);
        float dtv = softplusf(acc) * scale;
        float u = xm[(size_t)r * 512 + d];
        dtpack[(size_t)r * 512 + d] = make_float2(dtv, dtv * u);
    }
}

// ---------------------------------------------------------------------------
// Selective scan: one wave per (b,d), lane = state n; T=8 steps/iter with
// deferred reduce-scatter butterfly. Software-pipelined depth-1: next tile's
// bc/dt loads issued while current tile computes; u/z loads issued at tile
// top (before the prefetch) so their waitcnt leaves the prefetch in flight.
// Emits split bf16 only (fp32 y was dead — gemm3 reads hi/lo).
// ---------------------------------------------------------------------------
__global__ __launch_bounds__(256, 4) void scan_k(
    const float2* __restrict__ dtpack, const float* __restrict__ bcp,
    const float* __restrict__ xm, const float* __restrict__ xz,
    const float* __restrict__ A_log, const float* __restrict__ D_skip,
    unsigned short* __restrict__ yf_hi, unsigned short* __restrict__ yf_lo)
{
    int wv0  = blockIdx.x * 4 + (threadIdx.x >> 6);      // 0..4095
    int wv   = __builtin_amdgcn_readfirstlane(wv0);
    int lane = threadIdx.x & 63;
    int b = wv >> 9;
    int d = wv & 511;

    float A  = -__expf(A_log[d * 64 + lane]);
    float Dd = D_skip[d];

    const float2* dtp = dtpack + (size_t)b * LSEQ * 512 + d;
    const float*  bcr = bcp + (size_t)b * LSEQ * 128 + 2 * lane;
    const float*  xmb = xm  + (size_t)b * LSEQ * 512 + d;
    const float*  xzb = xz  + (size_t)b * LSEQ * 1024 + 512 + d;
    unsigned short* yph = yf_hi + (size_t)b * LSEQ * 512 + d;
    unsigned short* ypl = yf_lo + (size_t)b * LSEQ * 512 + d;

    const bool lo32 = (lane & 32) == 0;
    const bool lo16 = (lane & 16) == 0;
    const bool lo8  = (lane & 8)  == 0;
    const bool store_lane = (lane & 7) == 0;
    const int  tsel = lane >> 3;

    float h = 0.f;

    // ping-pong prefetch buffers (all 32-bit offsets; everything fits)
    float2 bcA[8], bcB[8], dqA[8], dqB[8];
    float uA, zA, uB, zB;

#define PREF(BC, DQ, L0)                                        \
    _Pragma("unroll")                                           \
    for (int t = 0; t < 8; t++) {                               \
        BC[t] = *(const float2*)&bcr[((L0) + t) * 128];         \
        DQ[t] = dtp[((L0) + t) * 512];                          \
    }

#define UZ(U, Z, L0)                                            \
    {                                                           \
        U = 0.f; Z = 0.f;                                       \
        if (store_lane) {                                       \
            int lu = (L0) + tsel;                               \
            U = xmb[lu * 512];                                  \
            Z = xzb[lu * 1024];                                 \
        }                                                       \
    }

#define STEP(BC, DQ, U, Z, L0)                                  \
    {                                                           \
        float p[8];                                             \
        _Pragma("unroll")                                       \
        for (int t = 0; t < 8; t++) {                           \
            float e = __expf(DQ[t].x * A);                      \
            h = fmaf(e, h, DQ[t].y * BC[t].x);                  \
            p[t] = h * BC[t].y;                                 \
        }                                                       \
        float q[4];                                             \
        _Pragma("unroll")                                       \
        for (int i = 0; i < 4; i++) {                           \
            float keep = lo32 ? p[i] : p[i + 4];                \
            float send = lo32 ? p[i + 4] : p[i];                \
            q[i] = keep + __shfl_xor(send, 32, 64);             \
        }                                                       \
        float r2[2];                                            \
        _Pragma("unroll")                                       \
        for (int i = 0; i < 2; i++) {                           \
            float keep = lo16 ? q[i] : q[i + 2];                \
            float send = lo16 ? q[i + 2] : q[i];                \
            r2[i] = keep + __shfl_xor(send, 16, 64);            \
        }                                                       \
        float keepf = lo8 ? r2[0] : r2[1];                      \
        float sendf = lo8 ? r2[1] : r2[0];                      \
        float s = keepf + __shfl_xor(sendf, 8, 64);             \
        s += __shfl_xor(s, 4, 64);                              \
        s += __shfl_xor(s, 2, 64);                              \
        s += __shfl_xor(s, 1, 64);                              \
        if (store_lane) {                                       \
            int lu = (L0) + tsel;                               \
            float yv = (s + (U) * Dd) * siluf(Z);               \
            unsigned short hh = f2bf(yv);                       \
            yph[lu * 512] = hh;                                 \
            ypl[lu * 512] = f2bf(yv - bf2f(hh));                \
        }                                                       \
    }

    PREF(bcA, dqA, 0);
    int l0 = 0;
#pragma unroll 1
    for (int it = 0; it < 12; it++) {
        UZ(uA, zA, l0);
        PREF(bcB, dqB, l0 + 8);
        STEP(bcA, dqA, uA, zA, l0);
        UZ(uB, zB, l0 + 8);
        PREF(bcA, dqA, l0 + 16);
        STEP(bcB, dqB, uB, zB, l0 + 8);
        l0 += 16;
    }
    // tail: tile 24 (l0 == 192), already prefetched into A
    UZ(uA, zA, 192);
    STEP(bcA, dqA, uA, zA, 192);

#undef PREF
#undef UZ
#undef STEP
}

// ---------------------------------------------------------------------------
// LayerNorm over last dim (256) + gamma/beta, fp32 out
// ---------------------------------------------------------------------------
__global__ __launch_bounds__(256) void ln_k(
    const float* __restrict__ outp, const float* __restrict__ gamma,
    const float* __restrict__ beta, float* __restrict__ out)
{
    int r = blockIdx.x;
    int t = threadIdx.x;
    float v = outp[(size_t)r * 256 + t];
    float s = v, ss = v * v;
#pragma unroll
    for (int off = 32; off > 0; off >>= 1) {
        s  += __shfl_xor(s,  off, 64);
        ss += __shfl_xor(ss, off, 64);
    }
    __shared__ float red[8];
    int w = t >> 6;
    if ((t & 63) == 0) { red[w] = s; red[4 + w] = ss; }
    __syncthreads();
    s  = red[0] + red[1] + red[2] + red[3];
    ss = red[4] + red[5] + red[6] + red[7];
    float mu  = s * (1.f / 256.f);
    float var = ss * (1.f / 256.f) - mu * mu;
    if (var < 0.f) var = 0.f;
    float inv = rsqrtf(var + 1e-12f);
    float o = (v - mu) * inv * gamma[t] + beta[t];
    out[(size_t)r * 256 + t] = o;
}

// ---------------------------------------------------------------------------
extern "C" void kernel_launch(void* const* d_in, const int* in_sizes, int n_in,
                              void* d_out, int out_size, void* d_ws, size_t ws_size,
                              hipStream_t stream)
{
    const float* x       = (const float*)d_in[0];
    const float* cosp    = (const float*)d_in[1];
    const float* sinp    = (const float*)d_in[2];
    const float* dmag    = (const float*)d_in[3];
    const float* W_in    = (const float*)d_in[4];
    const float* conv_w  = (const float*)d_in[5];
    const float* conv_b  = (const float*)d_in[6];
    const float* W_x     = (const float*)d_in[7];
    const float* W_dt    = (const float*)d_in[8];
    const float* b_dt    = (const float*)d_in[9];
    const float* A_log   = (const float*)d_in[10];
    const float* D_skip  = (const float*)d_in[11];
    const float* W_out   = (const float*)d_in[12];
    const float* gamma   = (const float*)d_in[13];
    const float* beta    = (const float*)d_in[14];
    const float* W_phase = (const float*)d_in[15];
    float* out = (float*)d_out;

    char* ws = (char*)d_ws;
    float*  xz     = (float*)ws;  ws += (size_t)ROWS * 1024 * 4;
    float*  xm     = (float*)ws;  ws += (size_t)ROWS * 512 * 4;
    float*  xp     = (float*)ws;  ws += (size_t)ROWS * 144 * 4;
    float*  bcp    = (float*)ws;  ws += (size_t)ROWS * 128 * 4;
    float2* dtpack = (float2*)ws; ws += (size_t)ROWS * 512 * 8;
    float*  outp   = (float*)ws;  ws += (size_t)ROWS * 256 * 4;
    unsigned short* x_hi   = (unsigned short*)ws; ws += (size_t)ROWS * 256 * 2;
    unsigned short* x_lo   = (unsigned short*)ws; ws += (size_t)ROWS * 256 * 2;
    unsigned short* WiT_hi = (unsigned short*)ws; ws += (size_t)1024 * 256 * 2;
    unsigned short* WiT_lo = (unsigned short*)ws; ws += (size_t)1024 * 256 * 2;
    unsigned short* WxT_hi = (unsigned short*)ws; ws += (size_t)144 * 512 * 2;
    unsigned short* WxT_lo = (unsigned short*)ws; ws += (size_t)144 * 512 * 2;
    unsigned short* WoT_hi = (unsigned short*)ws; ws += (size_t)256 * 512 * 2;
    unsigned short* WoT_lo = (unsigned short*)ws; ws += (size_t)256 * 512 * 2;
    unsigned short* xm_hi  = (unsigned short*)ws; ws += (size_t)ROWS * 512 * 2;
    unsigned short* xm_lo  = (unsigned short*)ws; ws += (size_t)ROWS * 512 * 2;
    unsigned short* yf_hi  = (unsigned short*)ws; ws += (size_t)ROWS * 512 * 2;
    unsigned short* yf_lo  = (unsigned short*)ws; ws += (size_t)ROWS * 512 * 2;

    dim3 blk(256);
    prep_w_k   <<<dim3(3424),   blk, 0, stream>>>(x, W_in, W_x, W_out,
                                                  x_hi, x_lo, WiT_hi, WiT_lo,
                                                  WxT_hi, WxT_lo, WoT_hi, WoT_lo);
    gemm_mfma  <<<dim3(16, 25), blk, 0, stream>>>(x_hi, x_lo, WiT_hi, WiT_lo,
                                                  xz, ROWS, 1024, 256, nullptr);
    conv_silu_k<<<dim3(3200),   blk, 0, stream>>>(xz, conv_w, conv_b, xm, xm_hi, xm_lo);
    gemm_mfma  <<<dim3(3, 25),  blk, 0, stream>>>(xm_hi, xm_lo, WxT_hi, WxT_lo,
                                                  xp, ROWS, 144, 512, nullptr);
    pack_bc_k  <<<dim3(400),    blk, 0, stream>>>(cosp, sinp, W_phase, xp, bcp);
    dt_k       <<<dim3(1600),   blk, 0, stream>>>(xp, W_dt, b_dt, dmag, xm, dtpack);
    scan_k     <<<dim3(1024),   blk, 0, stream>>>(dtpack, bcp, xm, xz, A_log, D_skip,
                                                  yf_hi, yf_lo);
    gemm_mfma  <<<dim3(4, 25),  blk, 0, stream>>>(yf_hi, yf_lo, WoT_hi, WoT_lo,
                                                  outp, ROWS, 256, 512, x);
    ln_k       <<<dim3(1600),   blk, 0, stream>>>(outp, gamma, beta, out);
}